// Round 7
// baseline (402.917 us; speedup 1.0000x reference)
//
#include <hip/hip_runtime.h>

constexpr int B = 64;
constexpr int N = 8192;
constexpr int D = 256;
constexpr int K = 128;
constexpr int CHUNKS = 32;                 // chunks per batch
constexpr int RPC = N / CHUNKS;            // 256 rows per chunk (per block)
constexpr int NCAND = CHUNKS * K;          // 4096 candidates per batch
constexpr int REPS = 4;                    // DIAGNOSTIC: x4 stage-1 repetition
                                           // -> single ~440us dispatch ranks #1
                                           // in rocprof top-5, exposing true
                                           // hbm_gbps / VALUBusy / occupancy.
                                           // Idempotent: every rep recomputes
                                           // identical keys and rewrites cand
                                           // with identical values.

typedef unsigned long long ull;

// --- Stage 1: fused norm + local top-K (round-4 body, x REPS) ---------------
// Reduction op-order per row IDENTICAL to rounds 1-4 (lane partial
// x*x+y*y+z*z+w*w, then shfl_xor 32..1): bit-exact keys -> selection
// provably unchanged vs the passing rounds.
__global__ __launch_bounds__(256) void norm_select_kernel(const float* __restrict__ x,
                                                          ull* __restrict__ cand) {
    __shared__ ull skeys[RPC];                    // 2 KiB
    const int bid   = blockIdx.x;
    const int batch = bid >> 5;                   // / CHUNKS
    const int chunk = bid & (CHUNKS - 1);
    const int tid   = threadIdx.x;
    const int w     = tid >> 6;
    const int lane  = tid & 63;
    const size_t rowbase = (size_t)batch * N + (size_t)chunk * RPC;
    const float* wbase = x + (rowbase + (size_t)w * 64) * D;

    #pragma unroll 1
    for (int rep = 0; rep < REPS; ++rep) {
        // Each of 4 waves reduces its 64 consecutive rows.
        for (int it = 0; it < 64; ++it) {
            const float4 v = reinterpret_cast<const float4*>(wbase + (size_t)it * D)[lane];
            float s = v.x * v.x + v.y * v.y + v.z * v.z + v.w * v.w;
            #pragma unroll
            for (int off = 32; off > 0; off >>= 1)
                s += __shfl_xor(s, off, 64);
            if (lane == 0) {
                const int lrow = w * 64 + it;
                const int grow = chunk * RPC + lrow;          // row index in batch
                skeys[lrow] = ((ull)__float_as_uint(s) << 32)
                            | (unsigned int)(N - 1 - grow);   // stable tie-break
            }
        }
        __syncthreads();

        // All-pairs rank among 256 distinct keys (broadcast LDS reads);
        // top 128 write themselves to their exact rank slot (no atomics).
        const ull mine = skeys[tid];
        int rank = 0;
        for (int j = 0; j < RPC; ++j)
            rank += (skeys[j] > mine) ? 1 : 0;
        if (rank < K)
            cand[(size_t)bid * K + rank] = mine;              // global write:
                                                              // keeps rep live
        __syncthreads();                          // skeys reuse next rep
    }
}

// --- Stage 2: exact top-K over 4096 candidates + fused gather ---------------
// (byte-identical to round 4)
__global__ __launch_bounds__(1024) void topk_gather_kernel(const ull* __restrict__ cand_in,
                                                           const float* __restrict__ x,
                                                           float* __restrict__ out) {
    __shared__ ull keys[NCAND];                   // 32 KiB
    __shared__ unsigned int hist[256];
    __shared__ unsigned int seg[32];
    __shared__ ull s_prefix;
    __shared__ unsigned int s_krem;
    __shared__ int s_done;
    __shared__ unsigned int s_cnt;
    __shared__ ull sel[K];
    __shared__ int sorted_src[K];

    const int b    = blockIdx.x;
    const int tid  = threadIdx.x;
    const int lane = tid & 63;

    for (int i = tid; i < NCAND; i += 1024)
        keys[i] = cand_in[(size_t)b * NCAND + i];
    if (tid == 0) { s_prefix = 0ull; s_krem = K; s_done = 0; s_cnt = 0u; }
    __syncthreads();

    for (int p = 7; p >= 0; --p) {
        if (s_done) break;                         // uniform, barrier-separated
        const int shift = p * 8;
        const ull          prefix = s_prefix;
        const unsigned int krem   = s_krem;
        if (tid < 256) hist[tid] = 0u;
        __syncthreads();

        if (p == 7) {
            for (int i = tid; i < NCAND; i += 1024) {
                const unsigned int d = (unsigned int)(keys[i] >> 56);
                ull rem = __ballot(true);
                while (rem) {
                    const int leader = __ffsll(rem) - 1;
                    const unsigned int dl = __shfl(d, leader, 64);
                    const ull grp = __ballot(d == dl);
                    if (lane == leader) atomicAdd(&hist[dl], (unsigned int)__popcll(grp));
                    rem &= ~grp;
                }
            }
        } else {
            for (int i = tid; i < NCAND; i += 1024) {
                const ull key = keys[i];
                if ((key >> (shift + 8)) == (prefix >> (shift + 8)))
                    atomicAdd(&hist[(unsigned int)(key >> shift) & 255u], 1u);
            }
        }
        __syncthreads();

        if (tid < 32) {                            // segment sums of 8 bins
            unsigned int s = 0;
            #pragma unroll
            for (int d2 = 0; d2 < 8; ++d2) s += hist[tid * 8 + d2];
            seg[tid] = s;
        }
        __syncthreads();

        if (tid < 256) {
            unsigned int cnt_gt = 0;
            const int hiSeg = (tid >> 3) + 1;
            for (int s2 = hiSeg; s2 < 32; ++s2) cnt_gt += seg[s2];
            for (int d2 = tid + 1; d2 < hiSeg * 8; ++d2) cnt_gt += hist[d2];
            const unsigned int h = hist[tid];
            if (cnt_gt < krem && krem <= cnt_gt + h) {   // unique winner
                s_prefix = prefix | ((ull)tid << shift);
                s_krem   = krem - cnt_gt;
                if (h == krem - cnt_gt) s_done = 1;
            }
        }
        __syncthreads();
    }

    const ull T = s_prefix;
    for (int i = tid; i < NCAND; i += 1024) {
        const ull key = keys[i];
        if (key >= T) {
            const unsigned int pos = atomicAdd(&s_cnt, 1u);
            sel[pos] = key;
        }
    }
    __syncthreads();

    if (tid < K) {
        const ull key = sel[tid];
        int rank = 0;
        for (int j = 0; j < K; ++j) rank += (sel[j] > key) ? 1 : 0;
        sorted_src[rank] = N - 1 - (int)(key & 0xFFFFFFFFu);
    }
    __syncthreads();

    // Gather: wave per output row, float4 per lane (1 KiB coalesced).
    for (int r = tid >> 6; r < K; r += 16) {
        const int src = sorted_src[r];
        const float4 v = reinterpret_cast<const float4*>(x + ((size_t)b * N + src) * D)[lane];
        reinterpret_cast<float4*>(out + ((size_t)b * K + r) * D)[lane] = v;
    }
}

extern "C" void kernel_launch(void* const* d_in, const int* in_sizes, int n_in,
                              void* d_out, int out_size, void* d_ws, size_t ws_size,
                              hipStream_t stream) {
    const float* x = (const float*)d_in[0];
    float* out = (float*)d_out;
    ull* cand = (ull*)d_ws;                        // B*NCAND u64 = 2 MiB

    norm_select_kernel<<<B * CHUNKS, 256, 0, stream>>>(x, cand);
    topk_gather_kernel<<<B, 1024, 0, stream>>>(cand, x, out);
}

// Round 8
// 116.386 us; speedup vs baseline: 3.4619x; 3.4619x over previous
//
#include <hip/hip_runtime.h>

constexpr int B = 64;
constexpr int N = 8192;
constexpr int D = 256;
constexpr int K = 128;
constexpr int CHUNKS = 32;                 // chunks per batch
constexpr int RPC = N / CHUNKS;            // 256 rows per chunk (per block)
constexpr int NCAND = CHUNKS * K;          // 4096 candidates per batch
constexpr int TILE = 64;                   // rows per LDS tile (4 tiles/block)

typedef unsigned long long ull;

__device__ __forceinline__ int bitrev6(int l) {
    return ((l & 1) << 5) | ((l & 2) << 3) | ((l & 4) << 1)
         | ((l & 8) >> 1) | ((l & 16) >> 3) | ((l & 32) >> 5);
}

// --- Stage 1: norm + local top-K, butterfly-free hot loop -------------------
// Round-7 diagnostic: per-rep time was 110us regardless of HBM vs L3 source
// (FETCH 1.07GB for 2.15GB consumed, same dur) => issue/latency-bound on the
// 6-deep dependent shfl_xor chain per row, NOT BW-bound. Fix: hot loop is
// load -> 4 VALU -> ds_write (no cross-lane); reduction deferred to phase 2.
//
// BIT-EXACTNESS: the rounds-1-4 butterfly (off=32..1) equals the standard
// balanced pairwise tree over lane-partials in bit-reversed lane order
// (off=32 first => root split on bit0 => leaf k = lane bitrev6(k); FP add is
// commutative so each pair matches bitwise). We write partials at column
// bitrev6(lane) and fold the natural balanced tree sequentially => keys are
// bit-identical to rounds 1-4, selection provably unchanged.
__global__ __launch_bounds__(256) void norm_select_kernel(const float* __restrict__ x,
                                                          ull* __restrict__ cand) {
    __shared__ float part[TILE][65];              // 16.6 KiB, stride-65 pad
    __shared__ ull skeys[RPC];                    // 2 KiB
    const int bid   = blockIdx.x;
    const int batch = bid >> 5;                   // / CHUNKS
    const int chunk = bid & (CHUNKS - 1);
    const int tid   = threadIdx.x;
    const int w     = tid >> 6;
    const int lane  = tid & 63;
    const int brl   = bitrev6(lane);
    const size_t rowbase = (size_t)batch * N + (size_t)chunk * RPC;

    for (int tile = 0; tile < 4; ++tile) {
        // Wave w streams its 16 rows of this tile: load->VALU->ds_write only.
        const int r0 = w * 16;                    // wave's first row in tile
        const float* wbase = x + (rowbase + (size_t)(tile * TILE + r0)) * D;
        #pragma unroll
        for (int it0 = 0; it0 < 16; it0 += 4) {
            float4 v[4];
            #pragma unroll
            for (int u = 0; u < 4; ++u)
                v[u] = reinterpret_cast<const float4*>(wbase + (size_t)(it0 + u) * D)[lane];
            #pragma unroll
            for (int u = 0; u < 4; ++u)
                part[r0 + it0 + u][brl] = v[u].x * v[u].x + v[u].y * v[u].y
                                        + v[u].z * v[u].z + v[u].w * v[u].w;
        }
        __syncthreads();

        // Phase 2: thread t (<64) folds row t's 64 partials as the standard
        // balanced tree (== butterfly bits). Reads stride-65: conflict-free.
        if (tid < TILE) {
            float q[8];
            float g[8];
            #pragma unroll
            for (int grp = 0; grp < 8; ++grp) {
                #pragma unroll
                for (int j = 0; j < 8; ++j) q[j] = part[tid][grp * 8 + j];
                g[grp] = ((q[0] + q[1]) + (q[2] + q[3]))
                       + ((q[4] + q[5]) + (q[6] + q[7]));
            }
            const float s = ((g[0] + g[1]) + (g[2] + g[3]))
                          + ((g[4] + g[5]) + (g[6] + g[7]));
            const int grow = chunk * RPC + tile * TILE + tid;   // row in batch
            skeys[tile * TILE + tid] = ((ull)__float_as_uint(s) << 32)
                                     | (unsigned int)(N - 1 - grow);
        }
        __syncthreads();                          // part[] reused next tile
    }

    // All-pairs rank among 256 distinct keys (broadcast LDS reads);
    // top 128 write themselves to their exact rank slot (sorted, no atomics).
    const ull mine = skeys[tid];
    int rank = 0;
    for (int j = 0; j < RPC; ++j)
        rank += (skeys[j] > mine) ? 1 : 0;
    if (rank < K)
        cand[(size_t)bid * K + rank] = mine;
}

// --- Stage 2: exact top-K over 4096 candidates + fused gather ---------------
// (byte-identical to round 4)
__global__ __launch_bounds__(1024) void topk_gather_kernel(const ull* __restrict__ cand_in,
                                                           const float* __restrict__ x,
                                                           float* __restrict__ out) {
    __shared__ ull keys[NCAND];                   // 32 KiB
    __shared__ unsigned int hist[256];
    __shared__ unsigned int seg[32];
    __shared__ ull s_prefix;
    __shared__ unsigned int s_krem;
    __shared__ int s_done;
    __shared__ unsigned int s_cnt;
    __shared__ ull sel[K];
    __shared__ int sorted_src[K];

    const int b    = blockIdx.x;
    const int tid  = threadIdx.x;
    const int lane = tid & 63;

    for (int i = tid; i < NCAND; i += 1024)
        keys[i] = cand_in[(size_t)b * NCAND + i];
    if (tid == 0) { s_prefix = 0ull; s_krem = K; s_done = 0; s_cnt = 0u; }
    __syncthreads();

    for (int p = 7; p >= 0; --p) {
        if (s_done) break;                         // uniform, barrier-separated
        const int shift = p * 8;
        const ull          prefix = s_prefix;
        const unsigned int krem   = s_krem;
        if (tid < 256) hist[tid] = 0u;
        __syncthreads();

        if (p == 7) {
            for (int i = tid; i < NCAND; i += 1024) {
                const unsigned int d = (unsigned int)(keys[i] >> 56);
                ull rem = __ballot(true);
                while (rem) {
                    const int leader = __ffsll(rem) - 1;
                    const unsigned int dl = __shfl(d, leader, 64);
                    const ull grp = __ballot(d == dl);
                    if (lane == leader) atomicAdd(&hist[dl], (unsigned int)__popcll(grp));
                    rem &= ~grp;
                }
            }
        } else {
            for (int i = tid; i < NCAND; i += 1024) {
                const ull key = keys[i];
                if ((key >> (shift + 8)) == (prefix >> (shift + 8)))
                    atomicAdd(&hist[(unsigned int)(key >> shift) & 255u], 1u);
            }
        }
        __syncthreads();

        if (tid < 32) {                            // segment sums of 8 bins
            unsigned int s = 0;
            #pragma unroll
            for (int d2 = 0; d2 < 8; ++d2) s += hist[tid * 8 + d2];
            seg[tid] = s;
        }
        __syncthreads();

        if (tid < 256) {
            unsigned int cnt_gt = 0;
            const int hiSeg = (tid >> 3) + 1;
            for (int s2 = hiSeg; s2 < 32; ++s2) cnt_gt += seg[s2];
            for (int d2 = tid + 1; d2 < hiSeg * 8; ++d2) cnt_gt += hist[d2];
            const unsigned int h = hist[tid];
            if (cnt_gt < krem && krem <= cnt_gt + h) {   // unique winner
                s_prefix = prefix | ((ull)tid << shift);
                s_krem   = krem - cnt_gt;
                if (h == krem - cnt_gt) s_done = 1;
            }
        }
        __syncthreads();
    }

    const ull T = s_prefix;
    for (int i = tid; i < NCAND; i += 1024) {
        const ull key = keys[i];
        if (key >= T) {
            const unsigned int pos = atomicAdd(&s_cnt, 1u);
            sel[pos] = key;
        }
    }
    __syncthreads();

    if (tid < K) {
        const ull key = sel[tid];
        int rank = 0;
        for (int j = 0; j < K; ++j) rank += (sel[j] > key) ? 1 : 0;
        sorted_src[rank] = N - 1 - (int)(key & 0xFFFFFFFFu);
    }
    __syncthreads();

    // Gather: wave per output row, float4 per lane (1 KiB coalesced).
    for (int r = tid >> 6; r < K; r += 16) {
        const int src = sorted_src[r];
        const float4 v = reinterpret_cast<const float4*>(x + ((size_t)b * N + src) * D)[lane];
        reinterpret_cast<float4*>(out + ((size_t)b * K + r) * D)[lane] = v;
    }
}

extern "C" void kernel_launch(void* const* d_in, const int* in_sizes, int n_in,
                              void* d_out, int out_size, void* d_ws, size_t ws_size,
                              hipStream_t stream) {
    const float* x = (const float*)d_in[0];
    float* out = (float*)d_out;
    ull* cand = (ull*)d_ws;                        // B*NCAND u64 = 2 MiB

    norm_select_kernel<<<B * CHUNKS, 256, 0, stream>>>(x, cand);
    topk_gather_kernel<<<B, 1024, 0, stream>>>(cand, x, out);
}